// Round 1
// baseline (553.567 us; speedup 1.0000x reference)
//
#include <hip/hip_runtime.h>
#include <math.h>

// GDecode: logits[m,v] = sum_{h,k} phi[m, h*64+k] * psi[perm[h,v], k]; out = softmax_v(logits)
// M=2048 (B*N), C=512 (G*K), V=32000.
// Numerics: phi split hi/lo into f16 (Dekker), psi cast to f16 once; both halves hit the
// same f16(psi) B-tile -> error only from psi's 2^-11 rounding -> logit err std ~3e-3.

#define M_ROWS 2048
#define V_DIM  32000
#define C_DIM  512
#define G_DIM  8
#define K_DIM  64
#define BM     128
#define BV     128
#define BK     32
#define NVBLK  (V_DIM / BV)   // 250
#define LDS_ROW 40            // 32 + 8 pad (f16 units); 80 B row = 16B-aligned, 2-way max conflict

typedef _Float16 f16x8 __attribute__((ext_vector_type(8)));
typedef _Float16 f16x4 __attribute__((ext_vector_type(4)));
typedef float    f32x4 __attribute__((ext_vector_type(4)));

__global__ __launch_bounds__(256, 2) void gdecode_gemm(
    const float* __restrict__ phi, const float* __restrict__ psi,
    const int* __restrict__ perm, const int pstride,
    float* __restrict__ out, float* __restrict__ smax, float* __restrict__ ssum)
{
  __shared__ __align__(16) _Float16 lds[3 * BM * LDS_ROW];
  _Float16* sAhi = lds;
  _Float16* sAlo = lds + BM * LDS_ROW;
  _Float16* sB   = lds + 2 * BM * LDS_ROW;

  const int t     = threadIdx.x;
  const int vbase = blockIdx.x * BV;
  const int mbase = blockIdx.y * BM;

  // staging map: kg = 4-float k-group, r0 = row (4 rows per thread, stride 32)
  const int kg = t & 7;
  const int r0 = t >> 3;

  // compute map: 4 waves as 2x2 of 64x64; each wave 4x4 grid of 16x16 MFMA tiles
  const int wid  = t >> 6;
  const int lane = t & 63;
  const int wm   = wid & 1;
  const int wv   = wid >> 1;
  const int lrow = lane & 15;
  const int quad = lane >> 4;

  f32x4 acc[4][4] = {};

  for (int it = 0; it < 16; ++it) {
    const int cb  = it * BK;      // column base in [0,512)
    const int h   = cb >> 6;      // group element
    const int kin = cb & 63;      // k offset inside psi row

    // global loads early (overlap previous iteration's MFMA)
    float4 av[4], bv[4];
    #pragma unroll
    for (int i = 0; i < 4; ++i) {
      int m = r0 + i * 32;
      av[i] = *(const float4*)(phi + (size_t)(mbase + m) * C_DIM + cb + kg * 4);
    }
    #pragma unroll
    for (int i = 0; i < 4; ++i) {
      int v  = r0 + i * 32;
      int pr = perm[(size_t)(h * V_DIM + vbase + v) * pstride];
      bv[i]  = *(const float4*)(psi + (size_t)pr * K_DIM + kin + kg * 4);
    }

    __syncthreads();   // previous iteration's LDS reads done

    #pragma unroll
    for (int i = 0; i < 4; ++i) {
      int m = r0 + i * 32;
      float4 x = av[i];
      _Float16 h0 = (_Float16)x.x, h1 = (_Float16)x.y,
               h2 = (_Float16)x.z, h3 = (_Float16)x.w;
      f16x4 hi = {h0, h1, h2, h3};
      f16x4 lo = {(_Float16)(x.x - (float)h0), (_Float16)(x.y - (float)h1),
                  (_Float16)(x.z - (float)h2), (_Float16)(x.w - (float)h3)};
      *(f16x4*)(sAhi + m * LDS_ROW + kg * 4) = hi;
      *(f16x4*)(sAlo + m * LDS_ROW + kg * 4) = lo;
    }
    #pragma unroll
    for (int i = 0; i < 4; ++i) {
      int v = r0 + i * 32;
      float4 x = bv[i];
      f16x4 w = {(_Float16)x.x, (_Float16)x.y, (_Float16)x.z, (_Float16)x.w};
      *(f16x4*)(sB + v * LDS_ROW + kg * 4) = w;
    }

    __syncthreads();   // tiles visible

    f16x8 ah[4], al[4], bf[4];
    #pragma unroll
    for (int i = 0; i < 4; ++i) {
      ah[i] = *(const f16x8*)(sAhi + (wm * 64 + i * 16 + lrow) * LDS_ROW + quad * 8);
      al[i] = *(const f16x8*)(sAlo + (wm * 64 + i * 16 + lrow) * LDS_ROW + quad * 8);
      bf[i] = *(const f16x8*)(sB   + (wv * 64 + i * 16 + lrow) * LDS_ROW + quad * 8);
    }
    #pragma unroll
    for (int i = 0; i < 4; ++i) {
      #pragma unroll
      for (int j = 0; j < 4; ++j) {
        acc[i][j] = __builtin_amdgcn_mfma_f32_16x16x32_f16(ah[i], bf[j], acc[i][j], 0, 0, 0);
        acc[i][j] = __builtin_amdgcn_mfma_f32_16x16x32_f16(al[i], bf[j], acc[i][j], 0, 0, 0);
      }
    }
  }

  // ---- epilogue: per-(row, vtile) stats + raw logit store ----
  __syncthreads();
  float* redmax = (float*)lds;        // [BM][2]
  float* redsum = redmax + 2 * BM;    // [BM][2]
  const int rowb = wm * 64;

  // per-row max over this wave's 64 columns (j in regs, 16 lanes via xor-shuffle)
  #pragma unroll
  for (int i = 0; i < 4; ++i) {
    #pragma unroll
    for (int r = 0; r < 4; ++r) {
      float v = fmaxf(fmaxf(acc[i][0][r], acc[i][1][r]),
                      fmaxf(acc[i][2][r], acc[i][3][r]));
      v = fmaxf(v, __shfl_xor(v, 1));
      v = fmaxf(v, __shfl_xor(v, 2));
      v = fmaxf(v, __shfl_xor(v, 4));
      v = fmaxf(v, __shfl_xor(v, 8));
      if (lrow == 0) redmax[(rowb + i * 16 + quad * 4 + r) * 2 + wv] = v;
    }
  }
  __syncthreads();
  float gmx[4][4];
  #pragma unroll
  for (int i = 0; i < 4; ++i) {
    #pragma unroll
    for (int r = 0; r < 4; ++r) {
      int row = rowb + i * 16 + quad * 4 + r;
      gmx[i][r] = fmaxf(redmax[row * 2], redmax[row * 2 + 1]);
    }
  }
  #pragma unroll
  for (int i = 0; i < 4; ++i) {
    #pragma unroll
    for (int r = 0; r < 4; ++r) {
      float s = __expf(acc[i][0][r] - gmx[i][r]) + __expf(acc[i][1][r] - gmx[i][r])
              + __expf(acc[i][2][r] - gmx[i][r]) + __expf(acc[i][3][r] - gmx[i][r]);
      s += __shfl_xor(s, 1);
      s += __shfl_xor(s, 2);
      s += __shfl_xor(s, 4);
      s += __shfl_xor(s, 8);
      if (lrow == 0) redsum[(rowb + i * 16 + quad * 4 + r) * 2 + wv] = s;
    }
  }
  __syncthreads();
  if (smax != nullptr && t < BM) {
    int row = t;
    size_t o = (size_t)(mbase + row) * NVBLK + blockIdx.x;
    smax[o] = fmaxf(redmax[row * 2], redmax[row * 2 + 1]);
    ssum[o] = redsum[row * 2] + redsum[row * 2 + 1];
  }
  // raw logits to d_out (normalized by kernel 2)
  #pragma unroll
  for (int i = 0; i < 4; ++i) {
    #pragma unroll
    for (int j = 0; j < 4; ++j) {
      #pragma unroll
      for (int r = 0; r < 4; ++r) {
        int grow = mbase + rowb + i * 16 + quad * 4 + r;
        int gcol = vbase + wv * 64 + j * 16 + lrow;
        out[(size_t)grow * V_DIM + gcol] = acc[i][j][r];
      }
    }
  }
}

// K2 (workspace path): combine 250 per-tile stats -> (M, S), then out = exp(l - M)/S
__global__ __launch_bounds__(256) void gdecode_softmax_ws(
    float* __restrict__ out, const float* __restrict__ smax, const float* __restrict__ ssum)
{
  __shared__ float sbuf[4];
  const int m = blockIdx.x;
  const int t = threadIdx.x;
  const float* rm = smax + (size_t)m * NVBLK;
  const float* rs = ssum + (size_t)m * NVBLK;

  float lm = -3.4e38f;
  for (int i = t; i < NVBLK; i += 256) lm = fmaxf(lm, rm[i]);
  for (int d = 1; d < 64; d <<= 1) lm = fmaxf(lm, __shfl_xor(lm, d));
  if ((t & 63) == 0) sbuf[t >> 6] = lm;
  __syncthreads();
  const float M = fmaxf(fmaxf(sbuf[0], sbuf[1]), fmaxf(sbuf[2], sbuf[3]));
  __syncthreads();

  float ls = 0.f;
  for (int i = t; i < NVBLK; i += 256) ls += rs[i] * __expf(rm[i] - M);
  for (int d = 1; d < 64; d <<= 1) ls += __shfl_xor(ls, d);
  if ((t & 63) == 0) sbuf[t >> 6] = ls;
  __syncthreads();
  const float inv = 1.f / (sbuf[0] + sbuf[1] + sbuf[2] + sbuf[3]);

  float4* row = (float4*)(out + (size_t)m * V_DIM);
  for (int i = t; i < V_DIM / 4; i += 256) {
    float4 x = row[i];
    x.x = __expf(x.x - M) * inv;
    x.y = __expf(x.y - M) * inv;
    x.z = __expf(x.z - M) * inv;
    x.w = __expf(x.w - M) * inv;
    row[i] = x;
  }
}

// K2 fallback (no workspace): scan the row itself for max and sum
__global__ __launch_bounds__(256) void gdecode_softmax_nows(float* __restrict__ out)
{
  __shared__ float sbuf[4];
  const int m = blockIdx.x;
  const int t = threadIdx.x;
  float4* row = (float4*)(out + (size_t)m * V_DIM);

  float lm = -3.4e38f;
  for (int i = t; i < V_DIM / 4; i += 256) {
    float4 x = row[i];
    lm = fmaxf(lm, fmaxf(fmaxf(x.x, x.y), fmaxf(x.z, x.w)));
  }
  for (int d = 1; d < 64; d <<= 1) lm = fmaxf(lm, __shfl_xor(lm, d));
  if ((t & 63) == 0) sbuf[t >> 6] = lm;
  __syncthreads();
  const float M = fmaxf(fmaxf(sbuf[0], sbuf[1]), fmaxf(sbuf[2], sbuf[3]));
  __syncthreads();

  float ls = 0.f;
  for (int i = t; i < V_DIM / 4; i += 256) {
    float4 x = row[i];
    ls += __expf(x.x - M) + __expf(x.y - M) + __expf(x.z - M) + __expf(x.w - M);
  }
  for (int d = 1; d < 64; d <<= 1) ls += __shfl_xor(ls, d);
  if ((t & 63) == 0) sbuf[t >> 6] = ls;
  __syncthreads();
  const float inv = 1.f / (sbuf[0] + sbuf[1] + sbuf[2] + sbuf[3]);

  for (int i = t; i < V_DIM / 4; i += 256) {
    float4 x = row[i];
    x.x = __expf(x.x - M) * inv;
    x.y = __expf(x.y - M) * inv;
    x.z = __expf(x.z - M) * inv;
    x.w = __expf(x.w - M) * inv;
    row[i] = x;
  }
}

extern "C" void kernel_launch(void* const* d_in, const int* in_sizes, int n_in,
                              void* d_out, int out_size, void* d_ws, size_t ws_size,
                              hipStream_t stream)
{
  const float* phi  = (const float*)d_in[0];   // [2048][512] fp32
  const float* psi  = (const float*)d_in[1];   // [32000][64] fp32
  const int*   perm = (const int*)d_in[2];     // [8][32000] int32 (stride guard below)
  // If the harness ever reports perm as raw int64 words (2x element count), read low words.
  const int pstride = (in_sizes[2] == 2 * G_DIM * V_DIM) ? 2 : 1;

  float* out = (float*)d_out;

  const size_t need = (size_t)M_ROWS * NVBLK * 2 * sizeof(float);
  const bool hasws = (d_ws != nullptr) && (ws_size >= need);
  float* smax = hasws ? (float*)d_ws : nullptr;
  float* ssum = hasws ? smax + (size_t)M_ROWS * NVBLK : nullptr;

  dim3 grid(NVBLK, M_ROWS / BM);   // 250 x 16
  gdecode_gemm<<<grid, 256, 0, stream>>>(phi, psi, perm, pstride, out, smax, ssum);

  if (hasws)
    gdecode_softmax_ws<<<M_ROWS, 256, 0, stream>>>(out, smax, ssum);
  else
    gdecode_softmax_nows<<<M_ROWS, 256, 0, stream>>>(out);
}